// Round 7
// 2855.138 us; speedup vs baseline: 1.6472x; 1.6472x over previous
//
#include <hip/hip_runtime.h>
#include <hip/hip_bf16.h>

#define VOCAB 50000
#define EMB   300
#define HID   1024
#define TT    512
#define BB    64

// Block layout for pre: [t][kb=64][row=64][c=16] bf16; per-t slab = 65536 shorts.
// h1/h2 are 2-slab rings in the same block layout (slab = t&1): the per-step
// all-to-all flag barrier guarantees everyone finished reading h[t-1] before
// any WG can be writing h[t+1] into the same slab.
//
// Pipelined scan: 128 WGs. WGs 0..63 = layer 0 (FUSE: also emits
// pre1[t-1] = h1[t-1]*W_ih1^T + b_ih1, via LDS tile -> full-line sc1 stores,
// drained before flagA[bx]=t+1). WGs 64..127 = layer 1, step t gated only on
// flagsA[bx] >= t+2 (its pre block [t][bx] is produced entirely by layer-0 WG
// bx during step t+1; tail sets flagA=TT+1=513 after pre1[511]).
// A never waits on B -> no deadlock cycle; B trails A by ~2 steps.
//
// NOTE: asm-load results must NEVER be live across a loop (spin) and should
// have SHORT straight-line live ranges — the allocator may spill an asm "=v"
// result to scratch BEFORE the load data lands (it treats the output as
// immediately valid) -> garbage. All load batches are issued and consumed in
// straight-line code, with binds as close to use as the pipeline allows.

typedef __attribute__((ext_vector_type(8))) short short8;
typedef __attribute__((ext_vector_type(4))) float floatx4;

__device__ inline float b2f(unsigned int u) {
    union { unsigned int i; float f; } v; v.i = u << 16; return v.f;
}
__device__ inline unsigned short f2b(float f) {
    __hip_bfloat16 h = __float2bfloat16(f);
    return *reinterpret_cast<unsigned short*>(&h);
}

// Wait until only N of the outstanding vector loads remain, binding the first
// 16 fragments "+v" so the compiler cannot consume them earlier.
#define WAIT_VM16(N, A) asm volatile("s_waitcnt vmcnt(" #N ")"              \
    : "+v"((A)[0]), "+v"((A)[1]), "+v"((A)[2]), "+v"((A)[3]),               \
      "+v"((A)[4]), "+v"((A)[5]), "+v"((A)[6]), "+v"((A)[7]),               \
      "+v"((A)[8]), "+v"((A)[9]), "+v"((A)[10]), "+v"((A)[11]),             \
      "+v"((A)[12]), "+v"((A)[13]), "+v"((A)[14]), "+v"((A)[15])            \
    :: "memory")

// ---------------------------------------------------------------------------
// detect: bf16 (mode=0) vs fp32 (mode=1) input buffers. Zeroes both flag sets.
// ctl ints: [0]=mode, flagsA=ctl+64 (64 flags stride 4), flagsB=ctl+320.
// ---------------------------------------------------------------------------
__global__ __launch_bounds__(64)
void detect_kernel(const void* __restrict__ W, int* __restrict__ ctl)
{
    const int tid = threadIdx.x;
    const unsigned short* p = (const unsigned short*)W;
    int bad = 0;
    for (int i = tid; i < 1024; i += 64) {
        float v = b2f(p[2 * i]);
        if (!(v > -0.5f && v < 0.5f)) bad++;
    }
    for (int off = 32; off; off >>= 1) bad += __shfl_down(bad, off);
    if (tid == 0) ctl[0] = (bad > 16) ? 1 : 0;
    for (int i = 64 + tid; i < 576; i += 64) ctl[i] = 0;
}

// ---------------------------------------------------------------------------
// proj (embedding gather): pre0[r][n] = bf16( emb[x]·W_ih0^T + b_ih0 ),
// written in BLOCK layout. 64 rows x 16 cols per WG.
// ---------------------------------------------------------------------------
__global__ __launch_bounds__(256)
void proj_kernel(const int*  __restrict__ xidx,
                 const void* __restrict__ emb,
                 const void* __restrict__ W,
                 const void* __restrict__ bias,
                 unsigned short* __restrict__ C,    // block layout bf16
                 const int* __restrict__ ctl)
{
    const int mode = ctl[0];
    const int K = EMB;
    __shared__ unsigned short Wl[16 * 312];          // KP2 = 312 >= 300
    const int tid = threadIdx.x;
    const int nb = blockIdx.x, mb = blockIdx.y;
    const int n0 = nb * 16;
    const int KP2 = 312;

    if (mode) {
        const float* Wf = (const float*)W;
        const int e4 = K >> 2, tot = 16 * e4;        // 300/4 = 75
        for (int i = tid; i < tot; i += 256) {
            int nl = i / e4, c = i - nl * e4;
            float4 f = *(const float4*)(Wf + (size_t)(n0 + nl) * K + c * 4);
            unsigned short* d = &Wl[nl * KP2 + c * 4];
            d[0] = f2b(f.x); d[1] = f2b(f.y); d[2] = f2b(f.z); d[3] = f2b(f.w);
        }
    } else {
        const unsigned short* Wb = (const unsigned short*)W;
        const int tot = 16 * K;
        for (int i = tid; i < tot; i += 256) {
            int nl = i / K, c = i - nl * K;
            Wl[nl * KP2 + c] = Wb[(size_t)(n0 + nl) * K + c];
        }
    }
    __syncthreads();

    const int wave = tid >> 6, lane = tid & 63;
    const int quad = lane >> 4, ln = lane & 15;
    const int r = mb * 64 + wave * 16 + ln;          // t = r>>6, b = r&63

    const unsigned short* Ab = nullptr;
    const float*          Af = nullptr;
    {
        int t = r >> 6, b = r & 63;
        size_t off = (size_t)xidx[b * TT + t] * K;
        if (mode) Af = (const float*)emb + off;
        else      Ab = (const unsigned short*)emb + off;
    }

    floatx4 acc = {0.f, 0.f, 0.f, 0.f};
    const int full = K >> 5;                         // 9
    for (int kk = 0; kk < full; ++kk) {
        int k = kk * 32 + quad * 8;
        short8 a;
        if (mode) {
            float4 f0 = *(const float4*)(Af + k);
            float4 f1 = *(const float4*)(Af + k + 4);
            a[0]=f2b(f0.x); a[1]=f2b(f0.y); a[2]=f2b(f0.z); a[3]=f2b(f0.w);
            a[4]=f2b(f1.x); a[5]=f2b(f1.y); a[6]=f2b(f1.z); a[7]=f2b(f1.w);
        } else {
            const uint2* ap = (const uint2*)(Ab + k);
            ((uint2*)&a)[0] = ap[0];
            ((uint2*)&a)[1] = ap[1];
        }
        short8 b = *(const short8*)&Wl[ln * KP2 + k];
        acc = __builtin_amdgcn_mfma_f32_16x16x32_bf16(a, b, acc, 0, 0, 0);
    }
    {   // K tail 288..299
        short8 a, b;
        for (int j = 0; j < 8; ++j) {
            int k = full * 32 + quad * 8 + j;
            bool in = (k < K);
            unsigned short raw = 0;
            if (in) raw = mode ? f2b(Af[k]) : Ab[k];
            a[j] = (short)raw;
            b[j] = in ? (short)Wl[ln * KP2 + k] : (short)0;
        }
        acc = __builtin_amdgcn_mfma_f32_16x16x32_bf16(a, b, acc, 0, 0, 0);
    }

    const int col = n0 + ln;
    const float bvf = mode ? ((const float*)bias)[col]
                           : b2f(((const unsigned short*)bias)[col]);
    for (int rg = 0; rg < 4; ++rg) {
        size_t addr = ((size_t)mb * 64 + nb) * 1024
                    + (size_t)(wave * 16 + quad * 4 + rg) * 16 + ln;
        C[addr] = f2b(acc[rg] + bvf);
    }
}

// ---------------------------------------------------------------------------
// scan2: both recurrences pipelined. 128 persistent WGs x 256 thr.
//   WG 0..63   (L=0): h1[t]=tanh(pre0[t]+h1[t-1]Whh0^T+bhh0), FUSE pre1[t-1].
//   WG 64..127 (L=1): h2[t]=tanh(pre1[t]+h2[t-1]Whh1^T+bhh1), gated on flagsA.
// ---------------------------------------------------------------------------
__global__ __launch_bounds__(256)
void scan2_kernel(unsigned short* __restrict__ preB,   // block layout bf16
                  unsigned short* __restrict__ h1B,    // 2-slab ring
                  unsigned short* __restrict__ h2B,    // 2-slab ring
                  const void* __restrict__ Whh0, const void* __restrict__ bhh0,
                  const void* __restrict__ Wih1, const void* __restrict__ bih1,
                  const void* __restrict__ Whh1, const void* __restrict__ bhh1,
                  int* __restrict__ ctl)
{
    const int mode = ctl[0];
    const int gbx  = blockIdx.x;
    const int L    = gbx >> 6;           // 0: layer0(+fuse), 1: layer1
    const int bx   = gbx & 63;
    const int n0   = bx * 16;
    int* flagsA    = ctl + 64;
    int* flagsSelf = ctl + (L ? 320 : 64);
    unsigned short* hB = L ? h2B : h1B;
    const void* Whh  = L ? Whh1 : Whh0;
    const void* bhhv = L ? bhh1 : bhh0;

    __shared__ unsigned short Wl[16 * 1032];
    __shared__ unsigned short Wn[16 * 1032];
    __shared__ __align__(16) unsigned short hTile[1024];
    __shared__ __align__(16) unsigned short pTile[1024];
    const int tid = threadIdx.x;

    if (mode) {
        const float* Wf = (const float*)Whh;
        for (int i = tid; i < 16 * 256; i += 256) {
            int nl = i >> 8, c = i & 255;
            float4 f = *(const float4*)(Wf + ((size_t)(n0 + nl) << 10) + c * 4);
            unsigned short* d = &Wl[nl * 1032 + c * 4];
            d[0] = f2b(f.x); d[1] = f2b(f.y); d[2] = f2b(f.z); d[3] = f2b(f.w);
        }
        if (L == 0) {
            const float* Wg = (const float*)Wih1;
            for (int i = tid; i < 16 * 256; i += 256) {
                int nl = i >> 8, c = i & 255;
                float4 f = *(const float4*)(Wg + ((size_t)(n0 + nl) << 10) + c * 4);
                unsigned short* d = &Wn[nl * 1032 + c * 4];
                d[0] = f2b(f.x); d[1] = f2b(f.y); d[2] = f2b(f.z); d[3] = f2b(f.w);
            }
        }
    } else {
        const unsigned short* Wb = (const unsigned short*)Whh;
        for (int i = tid; i < 16 * 128; i += 256) {
            int nl = i >> 7, c = i & 127;
            *(short8*)&Wl[nl * 1032 + c * 8] =
                *(const short8*)(Wb + ((size_t)(n0 + nl) << 10) + c * 8);
        }
        if (L == 0) {
            const unsigned short* Wg = (const unsigned short*)Wih1;
            for (int i = tid; i < 16 * 128; i += 256) {
                int nl = i >> 7, c = i & 127;
                *(short8*)&Wn[nl * 1032 + c * 8] =
                    *(const short8*)(Wg + ((size_t)(n0 + nl) << 10) + c * 8);
            }
        }
    }
    __syncthreads();

    const int wave = tid >> 6, lane = tid & 63;
    const int quad = lane >> 4, ln = lane & 15;
    const int brow = wave * 16 + ln;
    const int ncol = n0 + ln;
    const float bvf = mode ? ((const float*)bhhv)[ncol]
                           : b2f(((const unsigned short*)bhhv)[ncol]);
    const float bnf = (L == 0)
        ? (mode ? ((const float*)bih1)[ncol]
                : b2f(((const unsigned short*)bih1)[ncol]))
        : 0.f;
    const int b0 = wave * 16 + quad * 4;
    const unsigned short* wl = &Wl[ln * 1032 + quad * 8];
    const unsigned short* wn = &Wn[ln * 1032 + quad * 8];
    // per-lane base offset within an h slab: k = kk*32 + quad*8
    const int hoff = (quad >> 1) * 1024 + brow * 16 + (quad & 1) * 8;

    for (int t = 0; t < TT; ++t) {
        const unsigned short* pp = preB + (size_t)t * 65536 + (size_t)bx * 1024
                                        + (size_t)b0 * 16 + ln;
        unsigned int pr0, pr1, pr2, pr3;
        floatx4 acc  = {0.f, 0.f, 0.f, 0.f};
        floatx4 acc2 = {0.f, 0.f, 0.f, 0.f};

        if (L == 0) {
            // pre0[t]: written by proj (previous kernel) -> plain loads fine.
            pr0 = pp[0]; pr1 = pp[16]; pr2 = pp[32]; pr3 = pp[48];
            if (t > 0) {
                short8 a[32];
                const unsigned short* hp = hB + (size_t)((t - 1) & 1) * 65536 + hoff;
                #pragma unroll
                for (int kk = 0; kk < 32; ++kk)
                    asm volatile("global_load_dwordx4 %0, %1, off sc1"
                                 : "=v"(a[kk])
                                 : "v"(hp + (size_t)kk * 2048) : "memory");
                WAIT_VM16(16, a);   // a[0..15] done
                #pragma unroll
                for (int kk = 0; kk < 16; ++kk) {
                    short8 b  = *(const short8*)(wl + kk * 32);
                    short8 bn = *(const short8*)(wn + kk * 32);
                    acc  = __builtin_amdgcn_mfma_f32_16x16x32_bf16(a[kk], b,  acc,  0, 0, 0);
                    acc2 = __builtin_amdgcn_mfma_f32_16x16x32_bf16(a[kk], bn, acc2, 0, 0, 0);
                }
                WAIT_VM16(0, (a + 16));
                #pragma unroll
                for (int kk = 16; kk < 32; ++kk) {
                    short8 b  = *(const short8*)(wl + kk * 32);
                    short8 bn = *(const short8*)(wn + kk * 32);
                    acc  = __builtin_amdgcn_mfma_f32_16x16x32_bf16(a[kk], b,  acc,  0, 0, 0);
                    acc2 = __builtin_amdgcn_mfma_f32_16x16x32_bf16(a[kk], bn, acc2, 0, 0, 0);
                }
            }
        } else {
            // producer wait FIRST: no asm-load results may be live across a
            // variable-trip loop (spill-before-arrival hazard).
            {
                const int* fp = &flagsA[bx * 4];
                int v;
                do {
                    asm volatile("global_load_dword %0, %1, off sc1\n\t"
                                 "s_waitcnt vmcnt(0)"
                                 : "=v"(v) : "v"(fp) : "memory");
                } while (v < t + 2);
            }
            if (t > 0) {
                short8 a[32];
                const unsigned short* hp = hB + (size_t)((t - 1) & 1) * 65536 + hoff;
                #pragma unroll
                for (int kk = 0; kk < 32; ++kk)
                    asm volatile("global_load_dwordx4 %0, %1, off sc1"
                                 : "=v"(a[kk])
                                 : "v"(hp + (size_t)kk * 2048) : "memory");
                WAIT_VM16(16, a);    // a[0..15] done (16 of 32 remain)
                #pragma unroll
                for (int kk = 0; kk < 16; ++kk) {
                    short8 b = *(const short8*)(wl + kk * 32);
                    acc = __builtin_amdgcn_mfma_f32_16x16x32_bf16(a[kk], b, acc, 0, 0, 0);
                }
                // pre1[t] (sc1: written by layer-0 peer on another XCD).
                // Issued after a[16..31]; vmcnt counts in issue order, so
                // vmcnt(4) below completes all 16 older a-loads first.
                asm volatile("global_load_ushort %0, %1, off sc1"
                             : "=v"(pr0) : "v"(pp) : "memory");
                asm volatile("global_load_ushort %0, %1, off offset:32 sc1"
                             : "=v"(pr1) : "v"(pp) : "memory");
                asm volatile("global_load_ushort %0, %1, off offset:64 sc1"
                             : "=v"(pr2) : "v"(pp) : "memory");
                asm volatile("global_load_ushort %0, %1, off offset:96 sc1"
                             : "=v"(pr3) : "v"(pp) : "memory");
                WAIT_VM16(4, (a + 16));   // a[16..31] done; pr* still in flight
                #pragma unroll
                for (int kk = 16; kk < 32; ++kk) {
                    short8 b = *(const short8*)(wl + kk * 32);
                    acc = __builtin_amdgcn_mfma_f32_16x16x32_bf16(a[kk], b, acc, 0, 0, 0);
                }
            } else {
                asm volatile("global_load_ushort %0, %1, off sc1"
                             : "=v"(pr0) : "v"(pp) : "memory");
                asm volatile("global_load_ushort %0, %1, off offset:32 sc1"
                             : "=v"(pr1) : "v"(pp) : "memory");
                asm volatile("global_load_ushort %0, %1, off offset:64 sc1"
                             : "=v"(pr2) : "v"(pp) : "memory");
                asm volatile("global_load_ushort %0, %1, off offset:96 sc1"
                             : "=v"(pr3) : "v"(pp) : "memory");
            }
            // bind pr* at a real vmcnt(0), immediately before use
            asm volatile("s_waitcnt vmcnt(0)"
                         : "+v"(pr0), "+v"(pr1), "+v"(pr2), "+v"(pr3) :: "memory");
        }

        hTile[(b0 + 0) * 16 + ln] = f2b(tanhf(acc[0] + b2f(pr0) + bvf));
        hTile[(b0 + 1) * 16 + ln] = f2b(tanhf(acc[1] + b2f(pr1) + bvf));
        hTile[(b0 + 2) * 16 + ln] = f2b(tanhf(acc[2] + b2f(pr2) + bvf));
        hTile[(b0 + 3) * 16 + ln] = f2b(tanhf(acc[3] + b2f(pr3) + bvf));
        if (L == 0 && t > 0) {
            pTile[(b0 + 0) * 16 + ln] = f2b(acc2[0] + bnf);
            pTile[(b0 + 1) * 16 + ln] = f2b(acc2[1] + bnf);
            pTile[(b0 + 2) * 16 + ln] = f2b(acc2[2] + bnf);
            pTile[(b0 + 3) * 16 + ln] = f2b(acc2[3] + bnf);
        }
        __syncthreads();
        if (tid < 128) {   // 2 KB contiguous -> 32 full 64B lines each
            short8 hv = *(const short8*)&hTile[tid * 8];
            asm volatile("global_store_dwordx4 %0, %1, off sc1"
                         :: "v"(hB + (size_t)(t & 1) * 65536 + (size_t)bx * 1024 + tid * 8),
                            "v"(hv) : "memory");
            if (L == 0 && t > 0) {
                short8 pv = *(const short8*)&pTile[tid * 8];
                asm volatile("global_store_dwordx4 %0, %1, off sc1"
                             :: "v"(preB + (size_t)(t - 1) * 65536 + (size_t)bx * 1024 + tid * 8),
                                "v"(pv) : "memory");
            }
        }
        if (t < TT - 1) {
            asm volatile("s_waitcnt vmcnt(0)" ::: "memory");
            __syncthreads();
            if (tid == 0) {
                int tv = t + 1;
                asm volatile("global_store_dword %0, %1, off sc1"
                             :: "v"(&flagsSelf[bx * 4]), "v"(tv) : "memory");
            }
            if (tid < 64) {
                const int* fp = &flagsSelf[tid * 4];
                int v;
                do {
                    asm volatile("global_load_dword %0, %1, off sc1\n\t"
                                 "s_waitcnt vmcnt(0)"
                                 : "=v"(v) : "v"(fp) : "memory");
                } while (__any(v < t + 1));
            }
            __syncthreads();
        }
    }

    if (L == 0) {   // tail: pre1[511] needs full h1[511] -> one more barrier round
        asm volatile("s_waitcnt vmcnt(0)" ::: "memory");
        __syncthreads();
        if (tid == 0) {
            int tv = TT;   // also releases layer-1 t=510 (needs pre1[510])
            asm volatile("global_store_dword %0, %1, off sc1"
                         :: "v"(&flagsSelf[bx * 4]), "v"(tv) : "memory");
        }
        if (tid < 64) {
            const int* fp = &flagsSelf[tid * 4];
            int v;
            do {
                asm volatile("global_load_dword %0, %1, off sc1\n\t"
                             "s_waitcnt vmcnt(0)"
                             : "=v"(v) : "v"(fp) : "memory");
            } while (__any(v < TT));
        }
        __syncthreads();

        const unsigned short* hp = hB + (size_t)((TT - 1) & 1) * 65536 + hoff;
        short8 a[32];
        floatx4 acc2 = {0.f, 0.f, 0.f, 0.f};
        #pragma unroll
        for (int kk = 0; kk < 32; ++kk)
            asm volatile("global_load_dwordx4 %0, %1, off sc1"
                         : "=v"(a[kk])
                         : "v"(hp + (size_t)kk * 2048) : "memory");
        WAIT_VM16(16, a);
        #pragma unroll
        for (int kk = 0; kk < 16; ++kk) {
            short8 bn = *(const short8*)(wn + kk * 32);
            acc2 = __builtin_amdgcn_mfma_f32_16x16x32_bf16(a[kk], bn, acc2, 0, 0, 0);
        }
        WAIT_VM16(0, (a + 16));
        #pragma unroll
        for (int kk = 16; kk < 32; ++kk) {
            short8 bn = *(const short8*)(wn + kk * 32);
            acc2 = __builtin_amdgcn_mfma_f32_16x16x32_bf16(a[kk], bn, acc2, 0, 0, 0);
        }
        pTile[(b0 + 0) * 16 + ln] = f2b(acc2[0] + bnf);
        pTile[(b0 + 1) * 16 + ln] = f2b(acc2[1] + bnf);
        pTile[(b0 + 2) * 16 + ln] = f2b(acc2[2] + bnf);
        pTile[(b0 + 3) * 16 + ln] = f2b(acc2[3] + bnf);
        __syncthreads();
        if (tid < 128) {
            short8 pv = *(const short8*)&pTile[tid * 8];
            asm volatile("global_store_dwordx4 %0, %1, off sc1"
                         :: "v"(preB + (size_t)(TT - 1) * 65536 + (size_t)bx * 1024 + tid * 8),
                            "v"(pv) : "memory");
        }
        asm volatile("s_waitcnt vmcnt(0)" ::: "memory");
        __syncthreads();
        if (tid == 0) {
            int tv = TT + 1;   // releases layer-1 t=511
            asm volatile("global_store_dword %0, %1, off sc1"
                         :: "v"(&flagsSelf[bx * 4]), "v"(tv) : "memory");
        }
    }
}

// ---------------------------------------------------------------------------
// fc: out[b] = sigmoid(dot(h2[T-1][b], Wfc) + bfc) -- h2 ring slab (TT-1)&1
// ---------------------------------------------------------------------------
__global__ __launch_bounds__(1024)
void fc_kernel(const unsigned short* __restrict__ h,
               const void* __restrict__ Wfc,
               const void* __restrict__ bfc,
               float* __restrict__ out,
               const int* __restrict__ ctl)
{
    const int mode = ctl[0];
    const int tid = threadIdx.x;
    const int b = tid >> 4, sub = tid & 15;
    const unsigned short* hr = h + (size_t)((TT - 1) & 1) * 65536 + b * 16 + sub;
    float s = 0.f;
    for (int j = 0; j < 64; ++j) {          // k = j*16 + sub
        float w = mode ? ((const float*)Wfc)[j * 16 + sub]
                       : b2f(((const unsigned short*)Wfc)[j * 16 + sub]);
        s += b2f(hr[(size_t)j * 1024]) * w;
    }
    for (int off = 8; off; off >>= 1)
        s += __shfl_down(s, off, 16);
    if (sub == 0) {
        float bv = mode ? ((const float*)bfc)[0]
                        : b2f(((const unsigned short*)bfc)[0]);
        out[b] = 1.f / (1.f + expf(-(s + bv)));
    }
}

// ---------------------------------------------------------------------------
extern "C" void kernel_launch(void* const* d_in, const int* in_sizes, int n_in,
                              void* d_out, int out_size, void* d_ws, size_t ws_size,
                              hipStream_t stream)
{
    const int*  x    = (const int*)d_in[0];
    const void* emb  = d_in[1];
    const void* Wih0 = d_in[2];
    const void* Whh0 = d_in[3];
    const void* bih0 = d_in[4];
    const void* bhh0 = d_in[5];
    const void* Wih1 = d_in[6];
    const void* Whh1 = d_in[7];
    const void* bih1 = d_in[8];
    const void* bhh1 = d_in[9];
    const void* Wfc  = d_in[10];
    const void* bfc  = d_in[11];
    float* out = (float*)d_out;

    char* ws = (char*)d_ws;
    int*            ctl  = (int*)ws;                              // 4 KiB
    unsigned short* pre  = (unsigned short*)(ws + 4096);          // 64 MiB
    unsigned short* h1   = (unsigned short*)(ws + 4096 + (size_t)67108864); // 256 KiB ring
    unsigned short* h2   = h1 + 2 * 65536;                        // 256 KiB ring

    // dtype detect + flag zeroing
    detect_kernel<<<dim3(1), dim3(64), 0, stream>>>(Whh0, ctl);
    // layer 0 input projection (embedding gather) -> pre (block layout)
    proj_kernel<<<dim3(64, 512), dim3(256), 0, stream>>>(
        x, emb, Wih0, bih0, pre, ctl);
    // both recurrences, software-pipelined (layer 1 trails layer 0 by 2 steps)
    scan2_kernel<<<dim3(128), dim3(256), 0, stream>>>(
        pre, h1, h2, Whh0, bhh0, Wih1, bih1, Whh1, bhh1, ctl);
    // final FC + sigmoid
    fc_kernel<<<dim3(1), dim3(1024), 0, stream>>>(h2, Wfc, bfc, out, ctl);
}